// Round 1
// baseline (498.333 us; speedup 1.0000x reference)
//
#include <hip/hip_runtime.h>
#include <hip/hip_bf16.h>
#include <math.h>

typedef __hip_bfloat16 bf16;
typedef __attribute__((ext_vector_type(8))) short short8;
typedef __attribute__((ext_vector_type(4))) short short4v;
typedef __attribute__((ext_vector_type(4))) float f32x4;

#define SEQ 3072
#define HID 1152
#define NHEAD 16
#define HD 72
#define HDP 96
#define MLPD 4304
#define MLPP 4352

__device__ __forceinline__ void async_lds16(void* lds, const void* g) {
  __builtin_amdgcn_global_load_lds((const __attribute__((address_space(1))) void*)g,
                                   (__attribute__((address_space(3))) void*)lds,
                                   16, 0, 0);
}

__device__ __forceinline__ short bf16b(float x) {
  __hip_bfloat16 h = __float2bfloat16(x);
  return *reinterpret_cast<short*>(&h);
}

// ---------------- weight cast kernels ----------------
__global__ __launch_bounds__(256) void cast_bf16_k(const float* __restrict__ in,
                                                   bf16* __restrict__ out, int n4) {
  int stride = gridDim.x * blockDim.x;
  for (int i = blockIdx.x * blockDim.x + threadIdx.x; i < n4; i += stride) {
    float4 u = ((const float4*)in)[i];
    short4v w;
    w.x = bf16b(u.x); w.y = bf16b(u.y); w.z = bf16b(u.z); w.w = bf16b(u.w);
    ((short4v*)out)[i] = w;
  }
}

// out [Rp][C] from in [R][C], rows >= R zero-filled
__global__ __launch_bounds__(256) void cast_pad_rows_k(const float* __restrict__ in,
                                                       bf16* __restrict__ out,
                                                       int R, int C4, int n4) {
  int stride = gridDim.x * blockDim.x;
  for (int i = blockIdx.x * blockDim.x + threadIdx.x; i < n4; i += stride) {
    int r = i / C4;
    short4v w = {0, 0, 0, 0};
    if (r < R) {
      float4 u = ((const float4*)in)[i];
      w.x = bf16b(u.x); w.y = bf16b(u.y); w.z = bf16b(u.z); w.w = bf16b(u.w);
    }
    ((short4v*)out)[i] = w;
  }
}

// out [R][Cp] from in [R][C], cols >= C zero-filled
__global__ __launch_bounds__(256) void cast_pad_cols_k(const float* __restrict__ in,
                                                       bf16* __restrict__ out,
                                                       int C4, int Cp4, int n4) {
  int stride = gridDim.x * blockDim.x;
  for (int i = blockIdx.x * blockDim.x + threadIdx.x; i < n4; i += stride) {
    int r = i / Cp4, c4 = i - r * Cp4;
    short4v w = {0, 0, 0, 0};
    if (c4 < C4) {
      float4 u = ((const float4*)in)[r * C4 + c4];
      w.x = bf16b(u.x); w.y = bf16b(u.y); w.z = bf16b(u.z); w.w = bf16b(u.w);
    }
    ((short4v*)out)[i] = w;
  }
}

// ---------------- layernorm (fp32 in -> bf16 out) ----------------
__global__ __launch_bounds__(256) void ln_k(const float* __restrict__ x,
                                            const float* __restrict__ g,
                                            const float* __restrict__ b,
                                            bf16* __restrict__ o) {
  int row = blockIdx.x;
  const float4* xr = (const float4*)(x + (size_t)row * HID);
  float sum = 0.f, sq = 0.f;
  for (int c = threadIdx.x; c < HID / 4; c += 256) {
    float4 u = xr[c];
    sum += u.x + u.y + u.z + u.w;
    sq += u.x * u.x + u.y * u.y + u.z * u.z + u.w * u.w;
  }
#pragma unroll
  for (int off = 32; off > 0; off >>= 1) {
    sum += __shfl_down(sum, off, 64);
    sq += __shfl_down(sq, off, 64);
  }
  __shared__ float red[8];
  int wv = threadIdx.x >> 6;
  if ((threadIdx.x & 63) == 0) { red[wv] = sum; red[4 + wv] = sq; }
  __syncthreads();
  if (threadIdx.x == 0) {
    red[0] = red[0] + red[1] + red[2] + red[3];
    red[4] = red[4] + red[5] + red[6] + red[7];
  }
  __syncthreads();
  float mu = red[0] * (1.f / HID);
  float var = red[4] * (1.f / HID) - mu * mu;
  float inv = rsqrtf(var + 1e-5f);
  short4v* o4 = (short4v*)(o + (size_t)row * HID);
  const float4* g4 = (const float4*)g;
  const float4* b4 = (const float4*)b;
  for (int c = threadIdx.x; c < HID / 4; c += 256) {
    float4 u = xr[c], gg = g4[c], bb = b4[c];
    short4v w;
    w.x = bf16b((u.x - mu) * inv * gg.x + bb.x);
    w.y = bf16b((u.y - mu) * inv * gg.y + bb.y);
    w.z = bf16b((u.z - mu) * inv * gg.z + bb.z);
    w.w = bf16b((u.w - mu) * inv * gg.w + bb.w);
    o4[c] = w;
  }
}

// ---------------- GEMM: C[M][N] = A[M][K] @ Bt[N][K]^T  (+ epilogue) ----------------
// EPI 0: +bias -> fp32   1: +bias+res -> fp32   2: +bias, gelu -> bf16
template <int EPI>
__global__ __launch_bounds__(256) void gemm_bf16(const bf16* __restrict__ A,
                                                 const bf16* __restrict__ Bt,
                                                 const float* __restrict__ bias, int nbias,
                                                 const float* __restrict__ res,
                                                 float* __restrict__ outf,
                                                 bf16* __restrict__ outb,
                                                 int M, int N, int K) {
  __shared__ bf16 As[128 * 32];
  __shared__ bf16 Bs[128 * 32];
  const int t = threadIdx.x;
  const int l = t & 63;
  const int w = t >> 6;
  const int wr = w >> 1, wc = w & 1;
  const int lrow = l & 15;
  const int lk = (l >> 4) * 8;
  const int m0 = blockIdx.y * 128;
  const int n0 = blockIdx.x * 128;
  const int arow = t >> 2;
  const int ach = (t & 3) * 8;

  f32x4 acc[4][4] = {};
  const int nkt = K >> 5;
  for (int kt = 0; kt < nkt; ++kt) {
    const int k0 = kt * 32;
    __syncthreads();
#pragma unroll
    for (int j = 0; j < 2; ++j) {
      int r = arow + j * 64;
      async_lds16(&As[(j * 256 + t) * 8], &A[(size_t)(m0 + r) * K + k0 + ach]);
      async_lds16(&Bs[(j * 256 + t) * 8], &Bt[(size_t)(n0 + r) * K + k0 + ach]);
    }
    __syncthreads();
    short8 af[4], bfr[4];
#pragma unroll
    for (int i = 0; i < 4; ++i)
      af[i] = *(const short8*)&As[(wr * 64 + i * 16 + lrow) * 32 + lk];
#pragma unroll
    for (int i = 0; i < 4; ++i)
      bfr[i] = *(const short8*)&Bs[(wc * 64 + i * 16 + lrow) * 32 + lk];
#pragma unroll
    for (int i = 0; i < 4; ++i)
#pragma unroll
      for (int j = 0; j < 4; ++j)
        acc[i][j] = __builtin_amdgcn_mfma_f32_16x16x32_bf16(af[i], bfr[j], acc[i][j], 0, 0, 0);
  }

#pragma unroll
  for (int i = 0; i < 4; ++i) {
    int rowb = m0 + wr * 64 + i * 16 + (l >> 4) * 4;
#pragma unroll
    for (int j = 0; j < 4; ++j) {
      int col = n0 + wc * 64 + j * 16 + lrow;
      float bv = (col < nbias) ? bias[col] : 0.f;
#pragma unroll
      for (int r2 = 0; r2 < 4; ++r2) {
        size_t idx = (size_t)(rowb + r2) * N + col;
        float v = acc[i][j][r2] + bv;
        if (EPI == 0) {
          outf[idx] = v;
        } else if (EPI == 1) {
          outf[idx] = v + res[idx];
        } else {
          float gel = 0.5f * v * (1.f + tanhf(0.7978845608028654f * (v + 0.044715f * v * v * v)));
          outb[idx] = __float2bfloat16(gel);
        }
      }
    }
  }
}

// ---------------- rope + qkv split ----------------
// xqkv fp32 [SEQ][3*HID] -> qp [NH][SEQ][HDP] (scaled), kp [NH][SEQ][HDP], vt [NH][HDP][SEQ]
__global__ __launch_bounds__(256) void rope_split(const float* __restrict__ xqkv,
                                                  const float* __restrict__ cosb,
                                                  const float* __restrict__ sinb,
                                                  bf16* __restrict__ qp,
                                                  bf16* __restrict__ kp,
                                                  bf16* __restrict__ vt) {
  __shared__ bf16 vl[64][72];
  const int t = threadIdx.x;
  const int h = blockIdx.y;
  const int s0 = blockIdx.x * 64;
  const float scale = 0.11785113019775793f;  // 1/sqrt(72)
  for (int idx = t; idx < 64 * 48; idx += 256) {
    int sl = idx / 48, pi = idx - sl * 48;
    int srow = s0 + sl;
    size_t obase = ((size_t)h * SEQ + srow) * HDP + 2 * pi;
    if (pi < 36) {
      const float* xr = xqkv + (size_t)srow * (3 * HID) + h * HD + 2 * pi;
      float qr = xr[0], qi = xr[1];
      float kr = xr[HID], ki = xr[HID + 1];
      float c = cosb[srow * 36 + pi], sn = sinb[srow * 36 + pi];
      qp[obase] = __float2bfloat16((qr * c - qi * sn) * scale);
      qp[obase + 1] = __float2bfloat16((qr * sn + qi * c) * scale);
      kp[obase] = __float2bfloat16(kr * c - ki * sn);
      kp[obase + 1] = __float2bfloat16(kr * sn + ki * c);
    } else {
      bf16 z = __float2bfloat16(0.f);
      qp[obase] = z; qp[obase + 1] = z;
      kp[obase] = z; kp[obase + 1] = z;
    }
  }
  for (int idx = t; idx < 64 * 72; idx += 256) {
    int sl = idx / 72, d = idx - sl * 72;
    vl[sl][d] = __float2bfloat16(xqkv[(size_t)(s0 + sl) * (3 * HID) + 2 * HID + h * HD + d]);
  }
  __syncthreads();
  bf16 z = __float2bfloat16(0.f);
  for (int idx = t; idx < HDP * 64; idx += 256) {
    int d = idx / 64, sl = idx - d * 64;
    vt[((size_t)h * HDP + d) * SEQ + s0 + sl] = (d < 72) ? vl[sl][d] : z;
  }
}

// ---------------- flash attention ----------------
// qp scaled. out: attn_bf [SEQ][HID]
__global__ __launch_bounds__(256) void flash_attn(const bf16* __restrict__ q,
                                                  const bf16* __restrict__ kk,
                                                  const bf16* __restrict__ vT,
                                                  bf16* __restrict__ o) {
  __shared__ bf16 Ks[64 * 96];
  __shared__ bf16 Vs[96 * 64];
  __shared__ bf16 Pl[4][16 * 64];
  const int t = threadIdx.x;
  const int l = t & 63;
  const int w = t >> 6;
  const int lrow = l & 15;
  const int lk = (l >> 4) * 8;
  const int h = blockIdx.y;
  const int q0 = blockIdx.x * 64 + w * 16;

  short8 qf[3];
#pragma unroll
  for (int f = 0; f < 3; ++f)
    qf[f] = *(const short8*)&q[((size_t)h * SEQ + q0 + lrow) * HDP + f * 32 + lk];

  float m_r[4], l_r[4];
  f32x4 oa[5] = {};
#pragma unroll
  for (int r = 0; r < 4; ++r) { m_r[r] = -1e30f; l_r[r] = 0.f; }

  for (int kt = 0; kt < SEQ / 64; ++kt) {
    const int kv0 = kt * 64;
    __syncthreads();
#pragma unroll
    for (int j = 0; j < 3; ++j) {
      int c = j * 256 + t;
      async_lds16(&Ks[c * 8], &kk[((size_t)h * SEQ + kv0 + (c / 12)) * HDP + (c % 12) * 8]);
      async_lds16(&Vs[c * 8], &vT[((size_t)h * HDP + (c / 8)) * SEQ + kv0 + (c % 8) * 8]);
    }
    __syncthreads();
    f32x4 s[4] = {};
#pragma unroll
    for (int nf = 0; nf < 4; ++nf)
#pragma unroll
      for (int f = 0; f < 3; ++f) {
        short8 bfr = *(const short8*)&Ks[(nf * 16 + lrow) * 96 + f * 32 + lk];
        s[nf] = __builtin_amdgcn_mfma_f32_16x16x32_bf16(qf[f], bfr, s[nf], 0, 0, 0);
      }
#pragma unroll
    for (int r = 0; r < 4; ++r) {
      float rm = fmaxf(fmaxf(s[0][r], s[1][r]), fmaxf(s[2][r], s[3][r]));
#pragma unroll
      for (int off = 1; off < 16; off <<= 1) rm = fmaxf(rm, __shfl_xor(rm, off, 64));
      float mn = fmaxf(m_r[r], rm);
      float alpha = __expf(m_r[r] - mn);
      float rs = 0.f;
#pragma unroll
      for (int nf = 0; nf < 4; ++nf) {
        float pv = __expf(s[nf][r] - mn);
        s[nf][r] = pv;
        rs += pv;
      }
#pragma unroll
      for (int off = 1; off < 16; off <<= 1) rs += __shfl_xor(rs, off, 64);
      l_r[r] = l_r[r] * alpha + rs;
      m_r[r] = mn;
#pragma unroll
      for (int nf = 0; nf < 5; ++nf) oa[nf][r] *= alpha;
      int prow = (l >> 4) * 4 + r;
#pragma unroll
      for (int nf = 0; nf < 4; ++nf)
        Pl[w][prow * 64 + nf * 16 + lrow] = __float2bfloat16(s[nf][r]);
    }
#pragma unroll
    for (int kf = 0; kf < 2; ++kf) {
      short8 pa = *(const short8*)&Pl[w][lrow * 64 + kf * 32 + lk];
#pragma unroll
      for (int nf = 0; nf < 5; ++nf) {
        short8 bv = *(const short8*)&Vs[(nf * 16 + lrow) * 64 + kf * 32 + lk];
        oa[nf] = __builtin_amdgcn_mfma_f32_16x16x32_bf16(pa, bv, oa[nf], 0, 0, 0);
      }
    }
  }
#pragma unroll
  for (int nf = 0; nf < 5; ++nf) {
    int d = nf * 16 + lrow;
    if (d < HD) {
#pragma unroll
      for (int r = 0; r < 4; ++r) {
        int row = q0 + (l >> 4) * 4 + r;
        o[(size_t)row * HID + h * HD + d] = __float2bfloat16(oa[nf][r] / l_r[r]);
      }
    }
  }
}

// ---------------- launch ----------------
extern "C" void kernel_launch(void* const* d_in, const int* in_sizes, int n_in,
                              void* d_out, int out_size, void* d_ws, size_t ws_size,
                              hipStream_t stream) {
  (void)in_sizes; (void)n_in; (void)out_size;
  const float* hidden = (const float*)d_in[0];
  const float* cosb = (const float*)d_in[1];
  const float* sinb = (const float*)d_in[2];
  const float* ln0g = (const float*)d_in[3];
  const float* ln0b = (const float*)d_in[4];
  const float* ln1g = (const float*)d_in[5];
  const float* ln1b = (const float*)d_in[6];
  const float* wqkv = (const float*)d_in[7];
  const float* bqkv = (const float*)d_in[8];
  const float* wo = (const float*)d_in[9];
  const float* bo = (const float*)d_in[10];
  const float* w0 = (const float*)d_in[11];
  const float* b0 = (const float*)d_in[12];
  const float* w1 = (const float*)d_in[13];
  const float* b1 = (const float*)d_in[14];

  char* p = (char*)d_ws;
  auto alloc = [&](size_t n) {
    char* r = p;
    p += (n + 255) & ~(size_t)255;
    return r;
  };
  bf16* wqkv_bf = (bf16*)alloc((size_t)3 * HID * HID * 2);
  bf16* wo_bf = (bf16*)alloc((size_t)HID * HID * 2);
  bf16* fc0_bf = (bf16*)alloc((size_t)MLPP * HID * 2);
  bf16* fc1_bf = (bf16*)alloc((size_t)HID * MLPP * 2);
  bf16* ln0_bf = (bf16*)alloc((size_t)SEQ * HID * 2);
  float* xqkv = (float*)alloc((size_t)SEQ * 3 * HID * 4);
  bf16* qp = (bf16*)alloc((size_t)NHEAD * SEQ * HDP * 2);
  bf16* kp = (bf16*)alloc((size_t)NHEAD * SEQ * HDP * 2);
  bf16* vt = (bf16*)alloc((size_t)NHEAD * HDP * SEQ * 2);
  bf16* attn_bf = (bf16*)alloc((size_t)SEQ * HID * 2);
  float* h1 = (float*)alloc((size_t)SEQ * HID * 4);
  bf16* ln1_bf = (bf16*)alloc((size_t)SEQ * HID * 2);
  bf16* gelu_bf = (bf16*)alloc((size_t)SEQ * MLPP * 2);
  if ((size_t)(p - (char*)d_ws) > ws_size) return;

  dim3 blk(256);
  cast_bf16_k<<<2048, blk, 0, stream>>>(wqkv, wqkv_bf, 3 * HID * HID / 4);
  cast_bf16_k<<<1024, blk, 0, stream>>>(wo, wo_bf, HID * HID / 4);
  cast_pad_rows_k<<<2048, blk, 0, stream>>>(w0, fc0_bf, MLPD, HID / 4, MLPP * HID / 4);
  cast_pad_cols_k<<<2048, blk, 0, stream>>>(w1, fc1_bf, MLPD / 4, MLPP / 4, HID * MLPP / 4);
  ln_k<<<SEQ, blk, 0, stream>>>(hidden, ln0g, ln0b, ln0_bf);
  gemm_bf16<0><<<dim3(3 * HID / 128, SEQ / 128), blk, 0, stream>>>(
      ln0_bf, wqkv_bf, bqkv, 3 * HID, nullptr, xqkv, nullptr, SEQ, 3 * HID, HID);
  rope_split<<<dim3(SEQ / 64, NHEAD), blk, 0, stream>>>(xqkv, cosb, sinb, qp, kp, vt);
  flash_attn<<<dim3(SEQ / 64, NHEAD), blk, 0, stream>>>(qp, kp, vt, attn_bf);
  gemm_bf16<1><<<dim3(HID / 128, SEQ / 128), blk, 0, stream>>>(
      attn_bf, wo_bf, bo, HID, hidden, h1, nullptr, SEQ, HID, HID);
  ln_k<<<SEQ, blk, 0, stream>>>(h1, ln1g, ln1b, ln1_bf);
  gemm_bf16<2><<<dim3(MLPP / 128, SEQ / 128), blk, 0, stream>>>(
      ln1_bf, fc0_bf, b0, MLPD, nullptr, nullptr, gelu_bf, SEQ, MLPP, HID);
  gemm_bf16<1><<<dim3(HID / 128, SEQ / 128), blk, 0, stream>>>(
      gelu_bf, fc1_bf, b1, HID, h1, (float*)d_out, nullptr, SEQ, HID, MLPP);
}

// Round 2
// 470.000 us; speedup vs baseline: 1.0603x; 1.0603x over previous
//
#include <hip/hip_runtime.h>
#include <hip/hip_bf16.h>
#include <math.h>

typedef __hip_bfloat16 bf16;
typedef __attribute__((ext_vector_type(8))) short short8;
typedef __attribute__((ext_vector_type(4))) short short4v;
typedef __attribute__((ext_vector_type(4))) float f32x4;

#define SEQ 3072
#define HID 1152
#define NHEAD 16
#define HD 72
#define HDP 96
#define MLPD 4304
#define MLPP 4352

__device__ __forceinline__ void async_lds16(void* lds, const void* g) {
  __builtin_amdgcn_global_load_lds((const __attribute__((address_space(1))) void*)g,
                                   (__attribute__((address_space(3))) void*)lds,
                                   16, 0, 0);
}

__device__ __forceinline__ short bf16b(float x) {
  __hip_bfloat16 h = __float2bfloat16(x);
  return *reinterpret_cast<short*>(&h);
}

// ---------------- weight cast kernels ----------------
__global__ __launch_bounds__(256) void cast_bf16_k(const float* __restrict__ in,
                                                   bf16* __restrict__ out, int n4) {
  int stride = gridDim.x * blockDim.x;
  for (int i = blockIdx.x * blockDim.x + threadIdx.x; i < n4; i += stride) {
    float4 u = ((const float4*)in)[i];
    short4v w;
    w.x = bf16b(u.x); w.y = bf16b(u.y); w.z = bf16b(u.z); w.w = bf16b(u.w);
    ((short4v*)out)[i] = w;
  }
}

// out [Rp][C] from in [R][C], rows >= R zero-filled
__global__ __launch_bounds__(256) void cast_pad_rows_k(const float* __restrict__ in,
                                                       bf16* __restrict__ out,
                                                       int R, int C4, int n4) {
  int stride = gridDim.x * blockDim.x;
  for (int i = blockIdx.x * blockDim.x + threadIdx.x; i < n4; i += stride) {
    int r = i / C4;
    short4v w = {0, 0, 0, 0};
    if (r < R) {
      float4 u = ((const float4*)in)[i];
      w.x = bf16b(u.x); w.y = bf16b(u.y); w.z = bf16b(u.z); w.w = bf16b(u.w);
    }
    ((short4v*)out)[i] = w;
  }
}

// out [R][Cp] from in [R][C], cols >= C zero-filled
__global__ __launch_bounds__(256) void cast_pad_cols_k(const float* __restrict__ in,
                                                       bf16* __restrict__ out,
                                                       int C4, int Cp4, int n4) {
  int stride = gridDim.x * blockDim.x;
  for (int i = blockIdx.x * blockDim.x + threadIdx.x; i < n4; i += stride) {
    int r = i / Cp4, c4 = i - r * Cp4;
    short4v w = {0, 0, 0, 0};
    if (c4 < C4) {
      float4 u = ((const float4*)in)[r * C4 + c4];
      w.x = bf16b(u.x); w.y = bf16b(u.y); w.z = bf16b(u.z); w.w = bf16b(u.w);
    }
    ((short4v*)out)[i] = w;
  }
}

// ---------------- layernorm (fp32 in -> bf16 out) ----------------
__global__ __launch_bounds__(256) void ln_k(const float* __restrict__ x,
                                            const float* __restrict__ g,
                                            const float* __restrict__ b,
                                            bf16* __restrict__ o) {
  int row = blockIdx.x;
  const float4* xr = (const float4*)(x + (size_t)row * HID);
  float sum = 0.f, sq = 0.f;
  for (int c = threadIdx.x; c < HID / 4; c += 256) {
    float4 u = xr[c];
    sum += u.x + u.y + u.z + u.w;
    sq += u.x * u.x + u.y * u.y + u.z * u.z + u.w * u.w;
  }
#pragma unroll
  for (int off = 32; off > 0; off >>= 1) {
    sum += __shfl_down(sum, off, 64);
    sq += __shfl_down(sq, off, 64);
  }
  __shared__ float red[8];
  int wv = threadIdx.x >> 6;
  if ((threadIdx.x & 63) == 0) { red[wv] = sum; red[4 + wv] = sq; }
  __syncthreads();
  if (threadIdx.x == 0) {
    red[0] = red[0] + red[1] + red[2] + red[3];
    red[4] = red[4] + red[5] + red[6] + red[7];
  }
  __syncthreads();
  float mu = red[0] * (1.f / HID);
  float var = red[4] * (1.f / HID) - mu * mu;
  float inv = rsqrtf(var + 1e-5f);
  short4v* o4 = (short4v*)(o + (size_t)row * HID);
  const float4* g4 = (const float4*)g;
  const float4* b4 = (const float4*)b;
  for (int c = threadIdx.x; c < HID / 4; c += 256) {
    float4 u = xr[c], gg = g4[c], bb = b4[c];
    short4v w;
    w.x = bf16b((u.x - mu) * inv * gg.x + bb.x);
    w.y = bf16b((u.y - mu) * inv * gg.y + bb.y);
    w.z = bf16b((u.z - mu) * inv * gg.z + bb.z);
    w.w = bf16b((u.w - mu) * inv * gg.w + bb.w);
    o4[c] = w;
  }
}

// ---------------- GEMM: C[M][N] = A[M][K] @ Bt[N][K]^T  (+ epilogue) ----------------
// EPI 0: +bias -> fp32   1: +bias+res -> fp32   2: +bias, gelu -> bf16
template <int EPI>
__global__ __launch_bounds__(256) void gemm_bf16(const bf16* __restrict__ A,
                                                 const bf16* __restrict__ Bt,
                                                 const float* __restrict__ bias, int nbias,
                                                 const float* __restrict__ res,
                                                 float* __restrict__ outf,
                                                 bf16* __restrict__ outb,
                                                 int M, int N, int K) {
  __shared__ bf16 As[128 * 32];
  __shared__ bf16 Bs[128 * 32];
  const int t = threadIdx.x;
  const int l = t & 63;
  const int w = t >> 6;
  const int wr = w >> 1, wc = w & 1;
  const int lrow = l & 15;
  const int lk = (l >> 4) * 8;
  const int m0 = blockIdx.y * 128;
  const int n0 = blockIdx.x * 128;
  const int arow = t >> 2;
  const int ach = (t & 3) * 8;

  f32x4 acc[4][4] = {};
  const int nkt = K >> 5;
  for (int kt = 0; kt < nkt; ++kt) {
    const int k0 = kt * 32;
    __syncthreads();
#pragma unroll
    for (int j = 0; j < 2; ++j) {
      int r = arow + j * 64;
      async_lds16(&As[(j * 256 + t) * 8], &A[(size_t)(m0 + r) * K + k0 + ach]);
      async_lds16(&Bs[(j * 256 + t) * 8], &Bt[(size_t)(n0 + r) * K + k0 + ach]);
    }
    __syncthreads();
    short8 af[4], bfr[4];
#pragma unroll
    for (int i = 0; i < 4; ++i)
      af[i] = *(const short8*)&As[(wr * 64 + i * 16 + lrow) * 32 + lk];
#pragma unroll
    for (int i = 0; i < 4; ++i)
      bfr[i] = *(const short8*)&Bs[(wc * 64 + i * 16 + lrow) * 32 + lk];
#pragma unroll
    for (int i = 0; i < 4; ++i)
#pragma unroll
      for (int j = 0; j < 4; ++j)
        acc[i][j] = __builtin_amdgcn_mfma_f32_16x16x32_bf16(af[i], bfr[j], acc[i][j], 0, 0, 0);
  }

#pragma unroll
  for (int i = 0; i < 4; ++i) {
    int rowb = m0 + wr * 64 + i * 16 + (l >> 4) * 4;
#pragma unroll
    for (int j = 0; j < 4; ++j) {
      int col = n0 + wc * 64 + j * 16 + lrow;
      float bv = (col < nbias) ? bias[col] : 0.f;
#pragma unroll
      for (int r2 = 0; r2 < 4; ++r2) {
        size_t idx = (size_t)(rowb + r2) * N + col;
        float v = acc[i][j][r2] + bv;
        if (EPI == 0) {
          outf[idx] = v;
        } else if (EPI == 1) {
          outf[idx] = v + res[idx];
        } else {
          float gel = 0.5f * v * (1.f + tanhf(0.7978845608028654f * (v + 0.044715f * v * v * v)));
          outb[idx] = __float2bfloat16(gel);
        }
      }
    }
  }
}

// ---------------- rope + qkv split ----------------
__global__ __launch_bounds__(256) void rope_split(const float* __restrict__ xqkv,
                                                  const float* __restrict__ cosb,
                                                  const float* __restrict__ sinb,
                                                  bf16* __restrict__ qp,
                                                  bf16* __restrict__ kp,
                                                  bf16* __restrict__ vt) {
  __shared__ bf16 vl[64][72];
  const int t = threadIdx.x;
  const int h = blockIdx.y;
  const int s0 = blockIdx.x * 64;
  const float scale = 0.11785113019775793f;  // 1/sqrt(72)
  for (int idx = t; idx < 64 * 48; idx += 256) {
    int sl = idx / 48, pi = idx - sl * 48;
    int srow = s0 + sl;
    size_t obase = ((size_t)h * SEQ + srow) * HDP + 2 * pi;
    if (pi < 36) {
      const float* xr = xqkv + (size_t)srow * (3 * HID) + h * HD + 2 * pi;
      float qr = xr[0], qi = xr[1];
      float kr = xr[HID], ki = xr[HID + 1];
      float c = cosb[srow * 36 + pi], sn = sinb[srow * 36 + pi];
      qp[obase] = __float2bfloat16((qr * c - qi * sn) * scale);
      qp[obase + 1] = __float2bfloat16((qr * sn + qi * c) * scale);
      kp[obase] = __float2bfloat16(kr * c - ki * sn);
      kp[obase + 1] = __float2bfloat16(kr * sn + ki * c);
    } else {
      bf16 z = __float2bfloat16(0.f);
      qp[obase] = z; qp[obase + 1] = z;
      kp[obase] = z; kp[obase + 1] = z;
    }
  }
  for (int idx = t; idx < 64 * 72; idx += 256) {
    int sl = idx / 72, d = idx - sl * 72;
    vl[sl][d] = __float2bfloat16(xqkv[(size_t)(s0 + sl) * (3 * HID) + 2 * HID + h * HD + d]);
  }
  __syncthreads();
  bf16 z = __float2bfloat16(0.f);
  for (int idx = t; idx < HDP * 64; idx += 256) {
    int d = idx / 64, sl = idx - d * 64;
    vt[((size_t)h * HDP + d) * SEQ + s0 + sl] = (d < 72) ? vl[sl][d] : z;
  }
}

// ---------------- flash attention ----------------
// Chunk-major LDS layouts (16B chunks along the fast axis) -> conflict-free b128 reads.
// K logical [64 kv][96 d]: phys elem = (cb)*512 + row*8 + e, cb = colbyte/16
// V logical [96 d][64 kv]: phys elem = 6144 + cb*768 + row*8 + e
// P per-wave logical [16 q][64 k]: phys elem = cb*128 + row*8 + e
__global__ __launch_bounds__(512) void flash_attn(const bf16* __restrict__ q,
                                                  const bf16* __restrict__ kk,
                                                  const bf16* __restrict__ vT,
                                                  bf16* __restrict__ o) {
  __shared__ alignas(16) bf16 KV[2][12288];  // 24KB per buf: K 12 chunks*64 rows, V 8 chunks*96 rows
  __shared__ alignas(16) bf16 Pl[8][1024];   // per-wave 2KB
  const int t = threadIdx.x;
  const int l = t & 63;
  const int w = t >> 6;
  const int g = l >> 4;
  const int lrow = l & 15;
  const int h = blockIdx.y;
  const int q0 = blockIdx.x * 128 + w * 16;

  // staging: 1536 16B slots (768 K + 768 V), 3 per thread
  const bf16* srcp[3];
  int sadv[3];
#pragma unroll
  for (int i = 0; i < 3; ++i) {
    int s = t + i * 512;
    if (s < 768) {
      int c = s >> 6, row = s & 63;
      srcp[i] = kk + ((size_t)h * SEQ + row) * HDP + c * 8;
      sadv[i] = 64 * HDP;
    } else {
      int vid = s - 768;
      int c = vid / 96, row = vid - c * 96;
      srcp[i] = vT + ((size_t)h * HDP + row) * SEQ + c * 8;
      sadv[i] = 64;
    }
  }
  auto STAGE = [&](int buf) {
#pragma unroll
    for (int i = 0; i < 3; ++i) {
      async_lds16(&KV[buf][(size_t)(t + i * 512) * 8], srcp[i]);
      srcp[i] += sadv[i];
    }
  };

  short8 qf[3];
#pragma unroll
  for (int f = 0; f < 3; ++f)
    qf[f] = *(const short8*)&q[((size_t)h * SEQ + q0 + lrow) * HDP + f * 32 + g * 8];

  float m_r[4], l_r[4];
  f32x4 oa[5] = {};
#pragma unroll
  for (int r = 0; r < 4; ++r) { m_r[r] = -1e30f; l_r[r] = 0.f; }

  STAGE(0);
  for (int kt = 0; kt < SEQ / 64; ++kt) {
    const int buf = kt & 1;
    if (kt + 1 < SEQ / 64) {
      STAGE(buf ^ 1);
      asm volatile("s_waitcnt vmcnt(3)" ::: "memory");
    } else {
      asm volatile("s_waitcnt vmcnt(0)" ::: "memory");
    }
    __builtin_amdgcn_s_barrier();

    f32x4 s4[4] = {};
    __builtin_amdgcn_s_setprio(1);
#pragma unroll
    for (int nf = 0; nf < 4; ++nf)
#pragma unroll
      for (int f = 0; f < 3; ++f) {
        short8 bfr = *(const short8*)&KV[buf][(f * 4 + g) * 512 + (nf * 16 + lrow) * 8];
        s4[nf] = __builtin_amdgcn_mfma_f32_16x16x32_bf16(qf[f], bfr, s4[nf], 0, 0, 0);
      }
    __builtin_amdgcn_s_setprio(0);

#pragma unroll
    for (int r = 0; r < 4; ++r) {
      float rm = fmaxf(fmaxf(s4[0][r], s4[1][r]), fmaxf(s4[2][r], s4[3][r]));
#pragma unroll
      for (int off = 1; off < 16; off <<= 1) rm = fmaxf(rm, __shfl_xor(rm, off, 64));
      float mn = fmaxf(m_r[r], rm);
      float alpha = __expf(m_r[r] - mn);
      float rs = 0.f;
#pragma unroll
      for (int nf = 0; nf < 4; ++nf) {
        float pv = __expf(s4[nf][r] - mn);
        s4[nf][r] = pv;
        rs += pv;
      }
#pragma unroll
      for (int off = 1; off < 16; off <<= 1) rs += __shfl_xor(rs, off, 64);
      l_r[r] = l_r[r] * alpha + rs;
      m_r[r] = mn;
#pragma unroll
      for (int nf = 0; nf < 5; ++nf) oa[nf][r] *= alpha;
#pragma unroll
      for (int nf = 0; nf < 4; ++nf)
        Pl[w][(nf * 2 + (lrow >> 3)) * 128 + (g * 4 + r) * 8 + (lrow & 7)] =
            __float2bfloat16(s4[nf][r]);
    }

    __builtin_amdgcn_s_setprio(1);
#pragma unroll
    for (int kf = 0; kf < 2; ++kf) {
      short8 pa = *(const short8*)&Pl[w][(kf * 4 + g) * 128 + lrow * 8];
#pragma unroll
      for (int nf = 0; nf < 5; ++nf) {
        short8 bv = *(const short8*)&KV[buf][6144 + (kf * 4 + g) * 768 + (nf * 16 + lrow) * 8];
        oa[nf] = __builtin_amdgcn_mfma_f32_16x16x32_bf16(pa, bv, oa[nf], 0, 0, 0);
      }
    }
    __builtin_amdgcn_s_setprio(0);
    asm volatile("s_waitcnt lgkmcnt(0)" ::: "memory");
    __builtin_amdgcn_s_barrier();
  }

#pragma unroll
  for (int nf = 0; nf < 5; ++nf) {
    int d = nf * 16 + lrow;
    if (d < HD) {
#pragma unroll
      for (int r = 0; r < 4; ++r) {
        int row = q0 + g * 4 + r;
        o[(size_t)row * HID + h * HD + d] = __float2bfloat16(oa[nf][r] / l_r[r]);
      }
    }
  }
}

// ---------------- launch ----------------
extern "C" void kernel_launch(void* const* d_in, const int* in_sizes, int n_in,
                              void* d_out, int out_size, void* d_ws, size_t ws_size,
                              hipStream_t stream) {
  (void)in_sizes; (void)n_in; (void)out_size;
  const float* hidden = (const float*)d_in[0];
  const float* cosb = (const float*)d_in[1];
  const float* sinb = (const float*)d_in[2];
  const float* ln0g = (const float*)d_in[3];
  const float* ln0b = (const float*)d_in[4];
  const float* ln1g = (const float*)d_in[5];
  const float* ln1b = (const float*)d_in[6];
  const float* wqkv = (const float*)d_in[7];
  const float* bqkv = (const float*)d_in[8];
  const float* wo = (const float*)d_in[9];
  const float* bo = (const float*)d_in[10];
  const float* w0 = (const float*)d_in[11];
  const float* b0 = (const float*)d_in[12];
  const float* w1 = (const float*)d_in[13];
  const float* b1 = (const float*)d_in[14];

  char* p = (char*)d_ws;
  auto alloc = [&](size_t n) {
    char* r = p;
    p += (n + 255) & ~(size_t)255;
    return r;
  };
  bf16* wqkv_bf = (bf16*)alloc((size_t)3 * HID * HID * 2);
  bf16* wo_bf = (bf16*)alloc((size_t)HID * HID * 2);
  bf16* fc0_bf = (bf16*)alloc((size_t)MLPP * HID * 2);
  bf16* fc1_bf = (bf16*)alloc((size_t)HID * MLPP * 2);
  bf16* ln0_bf = (bf16*)alloc((size_t)SEQ * HID * 2);
  float* xqkv = (float*)alloc((size_t)SEQ * 3 * HID * 4);
  bf16* qp = (bf16*)alloc((size_t)NHEAD * SEQ * HDP * 2);
  bf16* kp = (bf16*)alloc((size_t)NHEAD * SEQ * HDP * 2);
  bf16* vt = (bf16*)alloc((size_t)NHEAD * HDP * SEQ * 2);
  bf16* attn_bf = (bf16*)alloc((size_t)SEQ * HID * 2);
  float* h1 = (float*)alloc((size_t)SEQ * HID * 4);
  bf16* ln1_bf = (bf16*)alloc((size_t)SEQ * HID * 2);
  bf16* gelu_bf = (bf16*)alloc((size_t)SEQ * MLPP * 2);
  if ((size_t)(p - (char*)d_ws) > ws_size) return;

  dim3 blk(256);
  cast_bf16_k<<<2048, blk, 0, stream>>>(wqkv, wqkv_bf, 3 * HID * HID / 4);
  cast_bf16_k<<<1024, blk, 0, stream>>>(wo, wo_bf, HID * HID / 4);
  cast_pad_rows_k<<<2048, blk, 0, stream>>>(w0, fc0_bf, MLPD, HID / 4, MLPP * HID / 4);
  cast_pad_cols_k<<<2048, blk, 0, stream>>>(w1, fc1_bf, MLPD / 4, MLPP / 4, HID * MLPP / 4);
  ln_k<<<SEQ, blk, 0, stream>>>(hidden, ln0g, ln0b, ln0_bf);
  gemm_bf16<0><<<dim3(3 * HID / 128, SEQ / 128), blk, 0, stream>>>(
      ln0_bf, wqkv_bf, bqkv, 3 * HID, nullptr, xqkv, nullptr, SEQ, 3 * HID, HID);
  rope_split<<<dim3(SEQ / 64, NHEAD), blk, 0, stream>>>(xqkv, cosb, sinb, qp, kp, vt);
  flash_attn<<<dim3(SEQ / 128, NHEAD), dim3(512), 0, stream>>>(qp, kp, vt, attn_bf);
  gemm_bf16<1><<<dim3(HID / 128, SEQ / 128), blk, 0, stream>>>(
      attn_bf, wo_bf, bo, HID, hidden, h1, nullptr, SEQ, HID, HID);
  ln_k<<<SEQ, blk, 0, stream>>>(h1, ln1g, ln1b, ln1_bf);
  gemm_bf16<2><<<dim3(MLPP / 128, SEQ / 128), blk, 0, stream>>>(
      ln1_bf, fc0_bf, b0, MLPD, nullptr, nullptr, gelu_bf, SEQ, MLPP, HID);
  gemm_bf16<1><<<dim3(HID / 128, SEQ / 128), blk, 0, stream>>>(
      gelu_bf, fc1_bf, b1, HID, h1, (float*)d_out, nullptr, SEQ, HID, MLPP);
}